// Round 1
// baseline (631.868 us; speedup 1.0000x reference)
//
#include <hip/hip_runtime.h>
#include <hip/hip_bf16.h>
#include <stdint.h>

#define TOKENS 8192
#define DDIM 1024
#define HDIM 4096
#define NEXP 8
#define MAXENT 16384
#define MAXTILES 135
#define BT_ESTR ((size_t)DDIM * (size_t)HDIM)

typedef __attribute__((ext_vector_type(4))) float f32x4;
typedef __attribute__((ext_vector_type(8))) short bf16x8;
typedef __attribute__((ext_vector_type(4))) int i32x4;

__device__ __forceinline__ unsigned short f2bf(float f) {
  __hip_bfloat16 h = __float2bfloat16(f);
  return __builtin_bit_cast(unsigned short, h);
}

__device__ __forceinline__ void gload16(const void* g, void* l) {
  __builtin_amdgcn_global_load_lds(
      (const __attribute__((address_space(1))) unsigned int*)g,
      (__attribute__((address_space(3))) unsigned int*)l, 16, 0, 0);
}

// ---------------- prep: counts, offsets, tile list, scatter ----------------

__global__ void moe_count(const int* __restrict__ idx, int* __restrict__ meta) {
  int t = blockIdx.x * 256 + threadIdx.x;
  if (t >= TOKENS) return;
  int e0 = idx[2 * t], e1 = idx[2 * t + 1];
  atomicAdd(&meta[e0], 1);
  if (e1 != e0) atomicAdd(&meta[e1], 1);
}

__global__ void moe_scan(int* __restrict__ meta) {
  if (threadIdx.x != 0 || blockIdx.x != 0) return;
  int s = 0;
  for (int e = 0; e < NEXP; ++e) { meta[16 + e] = s; meta[32 + e] = s; s += meta[e]; }
  meta[16 + NEXP] = s;
  int nt = 0;
  for (int e = 0; e < NEXP; ++e) {
    int m = (meta[e] + 127) >> 7;
    for (int t = 0; t < m; ++t) meta[64 + nt++] = e | (t << 8);
  }
  meta[48] = nt;
}

__global__ void moe_scatter(const int* __restrict__ idx, const float* __restrict__ ew,
                            int* __restrict__ meta, int* __restrict__ etok,
                            float* __restrict__ ewgt) {
  int t = blockIdx.x * 256 + threadIdx.x;
  if (t >= TOKENS) return;
  int e0 = idx[2 * t], e1 = idx[2 * t + 1];
  float a = ew[2 * t], b = ew[2 * t + 1];
  if (e0 == e1) {
    int p = atomicAdd(&meta[32 + e0], 1);
    etok[p] = t; ewgt[p] = a + b;
  } else {
    int p = atomicAdd(&meta[32 + e0], 1);
    etok[p] = t; ewgt[p] = a;
    int q = atomicAdd(&meta[32 + e1], 1);
    etok[q] = t; ewgt[q] = b;
  }
}

// ---------------- conversions ----------------

__global__ void cvt_x_bf16(const float* __restrict__ src, unsigned short* __restrict__ dst, int n8) {
  int i = blockIdx.x * 256 + threadIdx.x;
  if (i >= n8) return;
  const float4* s4 = (const float4*)src;
  float4 a = s4[2 * i], b = s4[2 * i + 1];
  union { unsigned short h[8]; i32x4 v; } o;
  o.h[0] = f2bf(a.x); o.h[1] = f2bf(a.y); o.h[2] = f2bf(a.z); o.h[3] = f2bf(a.w);
  o.h[4] = f2bf(b.x); o.h[5] = f2bf(b.y); o.h[6] = f2bf(b.z); o.h[7] = f2bf(b.w);
  ((i32x4*)dst)[i] = o.v;
}

// src [E][R][C] fp32 -> dst [E][C][R] bf16
__global__ void trans_cvt(const float* __restrict__ src, unsigned short* __restrict__ dst,
                          int R, int C) {
  __shared__ float tile[32][33];
  int e = blockIdx.z;
  const float* s = src + (size_t)e * R * C;
  unsigned short* d = dst + (size_t)e * R * C;
  int c0 = blockIdx.x * 32, r0 = blockIdx.y * 32;
  int tx = threadIdx.x, ty = threadIdx.y;
  for (int i = ty; i < 32; i += 8)
    tile[i][tx] = s[(size_t)(r0 + i) * C + c0 + tx];
  __syncthreads();
  for (int i = ty; i < 32; i += 8)
    d[(size_t)(c0 + i) * R + r0 + tx] = f2bf(tile[tx][i]);
}

// ---------------- GEMM (MODE 0: x@w1 -> silu -> h;  MODE 1: h@w2 -> out) ----------------
// 128x128 tile, BK=64, 4 waves (2x2), mfma 16x16x32 bf16, XOR-swizzled LDS.

template <int MODE>
__global__ __launch_bounds__(256, 2) void moe_gemm(
    const unsigned short* __restrict__ Abase,   // x_bf16 [TOKENS][DDIM] or h [MAXENT][HC]
    const unsigned short* __restrict__ Btbase,  // [E][N][K] bf16 (transposed weights)
    const float* __restrict__ bias,             // b1 [E][HDIM] or b2 [E][DDIM]
    const int* __restrict__ meta,
    const int* __restrict__ etok,
    const float* __restrict__ ewgt,
    unsigned short* __restrict__ Hbuf,          // MODE 0 output
    float* __restrict__ Out,                    // MODE 1 output
    int Astride, int BtRowStride,
    int nbase, int kbase, int Klen,
    int biasStride, int Hstride, int addbias) {
  const int* offsets = meta + 16;
  int ntiles = meta[48];
  if ((int)blockIdx.y >= ntiles) return;
  int te = meta[64 + blockIdx.y];
  int e = te & 255, mt = te >> 8;
  int off = offsets[e], cnt = offsets[e + 1] - off;
  if (mt * 128 >= cnt) return;
  int nt = blockIdx.x;
  int total = offsets[NEXP];

  __shared__ unsigned short As[128 * 64];
  __shared__ unsigned short Bs[128 * 64];

  int tid = threadIdx.x;
  int lane = tid & 63, wid = tid >> 6;
  int wr = wid >> 1, wc = wid & 1;

  // staging source pointers (4 16B units per thread for A and B)
  const char* srcA[4];
  const char* srcB[4];
  const unsigned short* BtE = Btbase + (size_t)e * BT_ESTR + (size_t)nbase * BtRowStride + kbase;
#pragma unroll
  for (int j = 0; j < 4; ++j) {
    int u = j * 256 + tid;
    int row = u >> 3, c = u & 7;
    int csrc = c ^ (row & 7);
    srcB[j] = (const char*)(BtE + (size_t)(nt * 128 + row) * BtRowStride + csrc * 8);
    if (MODE == 0) {
      int gi = off + mt * 128 + row;
      if (gi > total - 1) gi = total - 1;
      int tok = etok[gi];
      srcA[j] = (const char*)(Abase + (size_t)tok * Astride + csrc * 8);
    } else {
      int gi = off + mt * 128 + row;
      if (gi > MAXENT - 1) gi = MAXENT - 1;
      srcA[j] = (const char*)(Abase + (size_t)gi * Astride + csrc * 8);
    }
  }

  f32x4 acc[4][4];
#pragma unroll
  for (int m = 0; m < 4; ++m)
#pragma unroll
    for (int n = 0; n < 4; ++n) acc[m][n] = (f32x4){0.f, 0.f, 0.f, 0.f};

  int nk = Klen >> 6;
  for (int kt = 0; kt < nk; ++kt) {
    int kb = kt * 128;  // bytes advanced per row
#pragma unroll
    for (int j = 0; j < 4; ++j) {
      gload16(srcA[j] + kb, (char*)As + (j * 256 + wid * 64) * 16);
      gload16(srcB[j] + kb, (char*)Bs + (j * 256 + wid * 64) * 16);
    }
    __syncthreads();
#pragma unroll
    for (int ks = 0; ks < 2; ++ks) {
      bf16x8 af[4], bg[4];
#pragma unroll
      for (int m = 0; m < 4; ++m) {
        int row = wr * 64 + m * 16 + (lane & 15);
        int cu = (ks * 4 + (lane >> 4)) ^ (row & 7);
        af[m] = *(const bf16x8*)((const char*)As + row * 128 + cu * 16);
      }
#pragma unroll
      for (int n = 0; n < 4; ++n) {
        int row = wc * 64 + n * 16 + (lane & 15);
        int cu = (ks * 4 + (lane >> 4)) ^ (row & 7);
        bg[n] = *(const bf16x8*)((const char*)Bs + row * 128 + cu * 16);
      }
#pragma unroll
      for (int m = 0; m < 4; ++m)
#pragma unroll
        for (int n = 0; n < 4; ++n)
          acc[m][n] = __builtin_amdgcn_mfma_f32_16x16x32_bf16(af[m], bg[n], acc[m][n], 0, 0, 0);
    }
    __syncthreads();
  }

  int colb = nt * 128 + wc * 64;
  if (MODE == 0) {
#pragma unroll
    for (int m = 0; m < 4; ++m) {
#pragma unroll
      for (int r = 0; r < 4; ++r) {
        int row = wr * 64 + m * 16 + (lane >> 4) * 4 + r;
        int gm = mt * 128 + row;
        if (gm < cnt) {
          size_t hrow = (size_t)(off + gm) * Hstride;
#pragma unroll
          for (int n = 0; n < 4; ++n) {
            int col = colb + n * 16 + (lane & 15);
            float v = acc[m][n][r] + bias[e * biasStride + nbase + col];
            v = v / (1.f + __expf(-v));
            Hbuf[hrow + col] = f2bf(v);
          }
        }
      }
    }
  } else {
#pragma unroll
    for (int m = 0; m < 4; ++m) {
#pragma unroll
      for (int r = 0; r < 4; ++r) {
        int row = wr * 64 + m * 16 + (lane >> 4) * 4 + r;
        int gm = mt * 128 + row;
        if (gm < cnt) {
          int ent = off + gm;
          int tok = etok[ent];
          float wgt = ewgt[ent];
#pragma unroll
          for (int n = 0; n < 4; ++n) {
            int col = colb + n * 16 + (lane & 15);
            float v = acc[m][n][r];
            if (addbias) v += bias[e * biasStride + col];
            atomicAdd(Out + (size_t)tok * DDIM + col, v * wgt);
          }
        }
      }
    }
  }
}

// ---------------- host launch ----------------

extern "C" void kernel_launch(void* const* d_in, const int* in_sizes, int n_in,
                              void* d_out, int out_size, void* d_ws, size_t ws_size,
                              hipStream_t stream) {
  (void)in_sizes; (void)n_in;
  const float* x = (const float*)d_in[0];
  const int* eidx = (const int*)d_in[1];
  const float* ew = (const float*)d_in[2];
  const float* w1 = (const float*)d_in[3];
  const float* b1 = (const float*)d_in[4];
  const float* w2 = (const float*)d_in[5];
  const float* b2 = (const float*)d_in[6];
  float* out = (float*)d_out;

  char* w = (char*)d_ws;
  size_t o_meta = 0;                                   // 4096 B
  size_t o_etok = 4096;                                // 64 KiB
  size_t o_ewgt = o_etok + (size_t)MAXENT * 4;         // 64 KiB
  size_t o_x    = o_ewgt + (size_t)MAXENT * 4;         // 16 MiB
  size_t o_w1t  = o_x + (size_t)TOKENS * DDIM * 2;     // 64 MiB
  size_t o_w2t  = o_w1t + (size_t)NEXP * BT_ESTR * 2;  // 64 MiB
  size_t o_h    = o_w2t + (size_t)NEXP * BT_ESTR * 2;

  int S = 1;
  while (S < 32) {
    size_t need = o_h + (size_t)MAXENT * (HDIM / S) * 2;
    if (need <= ws_size) break;
    S *= 2;
  }
  int HC = HDIM / S;

  int* meta = (int*)(w + o_meta);
  int* etok = (int*)(w + o_etok);
  float* ewgt = (float*)(w + o_ewgt);
  unsigned short* xb = (unsigned short*)(w + o_x);
  unsigned short* w1t = (unsigned short*)(w + o_w1t);
  unsigned short* w2t = (unsigned short*)(w + o_w2t);
  unsigned short* hbuf = (unsigned short*)(w + o_h);

  hipMemsetAsync(w + o_meta, 0, 4096, stream);
  hipMemsetAsync(d_out, 0, (size_t)out_size * 4, stream);

  moe_count<<<TOKENS / 256, 256, 0, stream>>>(eidx, meta);
  moe_scan<<<1, 64, 0, stream>>>(meta);
  moe_scatter<<<TOKENS / 256, 256, 0, stream>>>(eidx, ew, meta, etok, ewgt);
  cvt_x_bf16<<<(TOKENS * DDIM / 8 + 255) / 256, 256, 0, stream>>>(x, xb, TOKENS * DDIM / 8);
  trans_cvt<<<dim3(HDIM / 32, DDIM / 32, NEXP), dim3(32, 8), 0, stream>>>(w1, w1t, DDIM, HDIM);
  trans_cvt<<<dim3(DDIM / 32, HDIM / 32, NEXP), dim3(32, 8), 0, stream>>>(w2, w2t, HDIM, DDIM);

  for (int s = 0; s < S; ++s) {
    moe_gemm<0><<<dim3(HC / 128, MAXTILES, 1), 256, 0, stream>>>(
        xb, w1t, b1, meta, etok, ewgt, hbuf, nullptr,
        DDIM, DDIM, s * HC, 0, DDIM, HDIM, HC, 0);
    moe_gemm<1><<<dim3(DDIM / 128, MAXTILES, 1), 256, 0, stream>>>(
        hbuf, w2t, b2, meta, etok, ewgt, nullptr, out,
        HC, HDIM, 0, s * HC, HC, DDIM, 0, (s == 0) ? 1 : 0);
  }
}